// Round 1
// baseline (499.325 us; speedup 1.0000x reference)
//
#include <hip/hip_runtime.h>

// Problem dims (fixed by setup_inputs): B=4,S=2048 -> M=8192; K=4096; N=4096; bits=4; group=128
#define KD 4096
#define ND 4096
#define GRP 32          // K / group_size = scale groups per output row
#define NT (KD / 64)    // 64 K-tiles of BK=64

typedef unsigned short u16;
typedef float   f32x4  __attribute__((ext_vector_type(4)));
typedef __bf16  bf16x8 __attribute__((ext_vector_type(8)));
typedef unsigned short u16x8 __attribute__((ext_vector_type(8)));
typedef unsigned short u16x4 __attribute__((ext_vector_type(4)));

__device__ __forceinline__ u16 f2bf(float f) {        // RNE float->bf16
  unsigned u = __float_as_uint(f);
  return (u16)((u + 0x7fffu + ((u >> 16) & 1u)) >> 16);
}

__device__ __forceinline__ void async16(const void* g, void* l) {
  // global -> LDS direct copy, 16B per lane, dest = wave-uniform base + lane*16
  __builtin_amdgcn_global_load_lds(
      (const __attribute__((address_space(1))) unsigned int*)g,
      (__attribute__((address_space(3))) unsigned int*)l, 16, 0, 0);
}

// ---------------- prepass: grid-stride, 2048 blocks ----------------
// Hypothesis test: old 40960-block launch (1 float4/thread) ran at ~1.1 TB/s;
// same traffic with 2048 persistent-ish blocks should hit streaming BW.
// W: N*K/8 = 2,097,152 int32 -> 4 iters/thread. x: M*K/4 = 8,388,608 float4 -> 16 iters.
__global__ __launch_bounds__(256) void prep_kernel(
    const int* __restrict__ qw, const float* __restrict__ scale,
    const float* __restrict__ zp, u16* __restrict__ wout,
    const float4* __restrict__ x, u16x4* __restrict__ xb, int nx) {
  const int nth = gridDim.x * 256;
  const int t0 = blockIdx.x * 256 + threadIdx.x;
  for (int idx = t0; idx < ND * (KD / 8); idx += nth) {
    int n = idx >> 9;                           // K/8 = 512 int32 per row
    int p = idx & 511;
    int g = p >> 4;                             // 8 values/int32, 128/group
    float s = scale[n * GRP + g];
    float bz = -s * zp[n * GRP + g];            // w = q*s - s*zp
    unsigned q = (unsigned)qw[idx];
    u16x8 hv;
#pragma unroll
    for (int i = 0; i < 8; ++i)
      hv[i] = f2bf(fmaf((float)((q >> (4 * i)) & 15u), s, bz));
    *(u16x8*)(wout + (size_t)idx * 8) = hv;
  }
  for (int i = t0; i < nx; i += nth) {
    float4 v = x[i];
    u16x4 h;
    h[0] = f2bf(v.x); h[1] = f2bf(v.y); h[2] = f2bf(v.z); h[3] = f2bf(v.w);
    xb[i] = h;
  }
}

// ---------------- main GEMM: 256x256 tile, BK=64, 8-phase counted-vmcnt schedule ----
// 8 waves (2M x 4N), per-wave output 128x64 (8x4 fragments of 16x16, 2 k-slices/tile).
// LDS: 2 dbuf x (256x64) bf16 for A and B = 128 KiB. One block/CU, 2 waves/SIMD.
// LDS swizzle (proven 0-conflict in prior kernel): 16B chunk c of row r at slot c^(r&7);
// global_load_lds dest is linear (base+lane*16), so source chunk is pre-permuted:
// lane l fetches source chunk (l&7)^(l>>3) of row l>>3.
// Phases per K-tile t (each: ds_reads | stage 1 half-tile | barrier | lgkmcnt0 | 16 MFMA | barrier):
//   P0: read a[0..4]x2,b[0..2]x2 (12), stage A(t+1,h1);  mfma lo x lo
//   P1: read b[2..4]x2 (4),           stage B(t+1,h0);   mfma lo x hi
//   P2: read a[4..8]x2 (8, reuse regs),stage B(t+1,h1);  mfma hi x lo
//   P3: no reads,                      stage A(t+2,h0);  mfma hi x hi; vmcnt; barrier
// Staging lead = 4 phases. P3 writes buf (t&1) = live buffer: safe because the last
// ds_reads of tile t are in P2, completed before P2's end barrier.
// vmcnt(2) at P3 leaves only A(t+2,h0) in flight and guarantees tile t+1 fully landed
// (inductive: <=2 carried + 8 issued, keep last 2). Tail (t+2>=NT): vmcnt(0) — with no
// P3 issue, vmcnt(2) would leave B(t+1,h1) un-landed.
// C/D: col = lane&15, row = (lane>>4)*4 + reg   [m89/m91-verified]
__global__ __launch_bounds__(512, 2) void gemm256(
    const u16* __restrict__ xb, const u16* __restrict__ wb,
    const float* __restrict__ bias, float* __restrict__ out) {
  __shared__ u16 As[2][256 * 64];
  __shared__ u16 Bs[2][256 * 64];
  const int tid = threadIdx.x;
  const int l = tid & 63, w = tid >> 6;
  const int wr = w >> 2, wc = w & 3;
  const int col = l & 15, quad = l >> 4, rsw = col & 7;
  const int lr = l >> 3, csrc = (l & 7) ^ lr;

  // bijective XCD-chunked swizzle (m204): XCD k gets a contiguous m-stripe
  const int id = blockIdx.y * gridDim.x + blockIdx.x;
  const int nwg = gridDim.x * gridDim.y;
  const int q = nwg >> 3, r = nwg & 7;
  const int xcd = id & 7, off = id >> 3;
  const int wgid = (xcd < r ? xcd * (q + 1) : r * (q + 1) + (xcd - r) * q) + off;
  const int nb = gridDim.x;                      // n-blocks per row
  const int m0 = (wgid / nb) * 256;
  const int n0 = (wgid % nb) * 256;

  const u16* asrc = xb + (size_t)(m0 + w * 16 + lr) * KD + csrc * 8;
  const u16* bsrc = wb + (size_t)(n0 + w * 16 + lr) * KD + csrc * 8;

#define STAGE_A(t, h)                                                      \
  do {                                                                     \
    const u16* _g = asrc + (size_t)((h) * 128) * KD + (t) * 64;            \
    u16* _l = &As[(t) & 1][((h) * 128 + w * 16) * 64];                     \
    async16(_g, _l);                                                       \
    async16(_g + (size_t)8 * KD, _l + 8 * 64);                             \
  } while (0)
#define STAGE_B(t, h)                                                      \
  do {                                                                     \
    const u16* _g = bsrc + (size_t)((h) * 128) * KD + (t) * 64;            \
    u16* _l = &Bs[(t) & 1][((h) * 128 + w * 16) * 64];                     \
    async16(_g, _l);                                                       \
    async16(_g + (size_t)8 * KD, _l + 8 * 64);                             \
  } while (0)
#define BAR()    asm volatile("s_barrier" ::: "memory")
#define LGKM0()  asm volatile("s_waitcnt lgkmcnt(0)" ::: "memory")
#define VMCNT2() asm volatile("s_waitcnt vmcnt(2)" ::: "memory")
#define VMCNT0() asm volatile("s_waitcnt vmcnt(0)" ::: "memory")
#define LDA(Ab, i, kk) \
  (*(const bf16x8*)&(Ab)[(wr * 128 + (i) * 16 + col) * 64 + ((((kk) * 4 + quad) ^ rsw) * 8)])
#define LDB(Bb, j, kk) \
  (*(const bf16x8*)&(Bb)[(wc * 64 + (j) * 16 + col) * 64 + ((((kk) * 4 + quad) ^ rsw) * 8)])

  f32x4 acc[8][4] = {};
  bf16x8 a[4][2], b[4][2];

  // prologue: tile0 fully + tile1 A-half0; vmcnt(2) lands tile0, keeps A(1,h0) in flight
  STAGE_A(0, 0); STAGE_A(0, 1); STAGE_B(0, 0); STAGE_B(0, 1);
  STAGE_A(1, 0);
  VMCNT2();
  BAR();

  for (int t = 0; t < NT; ++t) {
    const u16* Ab = As[t & 1];
    const u16* Bb = Bs[t & 1];

    // ---- P0 ----
#pragma unroll
    for (int i = 0; i < 4; ++i) { a[i][0] = LDA(Ab, i, 0); a[i][1] = LDA(Ab, i, 1); }
#pragma unroll
    for (int j = 0; j < 2; ++j) { b[j][0] = LDB(Bb, j, 0); b[j][1] = LDB(Bb, j, 1); }
    if (t + 1 < NT) STAGE_A(t + 1, 1);
    BAR();
    LGKM0();
    __builtin_amdgcn_s_setprio(1);
#pragma unroll
    for (int kk = 0; kk < 2; ++kk)
#pragma unroll
      for (int i = 0; i < 4; ++i)
#pragma unroll
        for (int j = 0; j < 2; ++j)
          acc[i][j] = __builtin_amdgcn_mfma_f32_16x16x32_bf16(a[i][kk], b[j][kk], acc[i][j], 0, 0, 0);
    __builtin_amdgcn_s_setprio(0);
    BAR();

    // ---- P1 ----
#pragma unroll
    for (int j = 2; j < 4; ++j) { b[j][0] = LDB(Bb, j, 0); b[j][1] = LDB(Bb, j, 1); }
    if (t + 1 < NT) STAGE_B(t + 1, 0);
    BAR();
    LGKM0();
    __builtin_amdgcn_s_setprio(1);
#pragma unroll
    for (int kk = 0; kk < 2; ++kk)
#pragma unroll
      for (int i = 0; i < 4; ++i)
#pragma unroll
        for (int j = 2; j < 4; ++j)
          acc[i][j] = __builtin_amdgcn_mfma_f32_16x16x32_bf16(a[i][kk], b[j][kk], acc[i][j], 0, 0, 0);
    __builtin_amdgcn_s_setprio(0);
    BAR();

    // ---- P2 ---- (a[] reused for the hi m-half)
#pragma unroll
    for (int i = 0; i < 4; ++i) { a[i][0] = LDA(Ab, i + 4, 0); a[i][1] = LDA(Ab, i + 4, 1); }
    if (t + 1 < NT) STAGE_B(t + 1, 1);
    BAR();
    LGKM0();
    __builtin_amdgcn_s_setprio(1);
#pragma unroll
    for (int kk = 0; kk < 2; ++kk)
#pragma unroll
      for (int i = 0; i < 4; ++i)
#pragma unroll
        for (int j = 0; j < 2; ++j)
          acc[4 + i][j] = __builtin_amdgcn_mfma_f32_16x16x32_bf16(a[i][kk], b[j][kk], acc[4 + i][j], 0, 0, 0);
    __builtin_amdgcn_s_setprio(0);
    BAR();

    // ---- P3 ----
    if (t + 2 < NT) STAGE_A(t + 2, 0);
    BAR();
    __builtin_amdgcn_s_setprio(1);
#pragma unroll
    for (int kk = 0; kk < 2; ++kk)
#pragma unroll
      for (int i = 0; i < 4; ++i)
#pragma unroll
        for (int j = 2; j < 4; ++j)
          acc[4 + i][j] = __builtin_amdgcn_mfma_f32_16x16x32_bf16(a[i][kk], b[j][kk], acc[4 + i][j], 0, 0, 0);
    __builtin_amdgcn_s_setprio(0);
    if (t + 2 < NT) VMCNT2(); else VMCNT0();
    BAR();
  }

  // epilogue: add bias, store fp32
#pragma unroll
  for (int j = 0; j < 4; ++j) {
    int n = n0 + wc * 64 + j * 16 + col;
    float bj = bias[n];
#pragma unroll
    for (int i = 0; i < 8; ++i) {
      int mrow = m0 + wr * 128 + i * 16 + quad * 4;
#pragma unroll
      for (int rr = 0; rr < 4; ++rr)
        out[(size_t)(mrow + rr) * ND + n] = acc[i][j][rr] + bj;
    }
  }
#undef STAGE_A
#undef STAGE_B
#undef BAR
#undef LGKM0
#undef VMCNT2
#undef VMCNT0
#undef LDA
#undef LDB
}

// ---------------- fallback GEMM (old 128x128 m97-style kernel, kept for small ws) ----
template <int XF32, int WQ>
__global__ __launch_bounds__(256, 3) void gemm_kernel(
    const u16*   __restrict__ xbp,
    const float* __restrict__ xf,
    const u16*   __restrict__ wbp,
    const int*   __restrict__ qw,
    const float* __restrict__ scale,
    const float* __restrict__ zp,
    const float* __restrict__ bias,
    float* __restrict__ out) {
  __shared__ u16 As[128 * 64];
  __shared__ u16 Bs[128 * 64];
  const int tid = threadIdx.x;
  const int l = tid & 63, w = tid >> 6;
  const int m0 = blockIdx.y * 128, n0 = blockIdx.x * 128;
  const int wm = (w >> 1) * 64, wn = (w & 1) * 64;
  const int col = l & 15, quad = l >> 4;
  const int rsw = col & 7;
  const int lr = l >> 3;
  const int csrc = (l & 7) ^ lr;
  f32x4 acc[4][4] = {};

  for (int k0 = 0; k0 < KD; k0 += 64) {
    __syncthreads();

    if constexpr (XF32) {
#pragma unroll
      for (int it = 0; it < 8; ++it) {
        int fi = it * 256 + tid;
        int row = fi >> 4, cs = fi & 15;
        float4 v = *(const float4*)(xf + (size_t)(m0 + row) * KD + k0 + cs * 4);
        u16x4 h;
        h[0] = f2bf(v.x); h[1] = f2bf(v.y); h[2] = f2bf(v.z); h[3] = f2bf(v.w);
        int slot = (cs >> 1) ^ (row & 7);
        *(u16x4*)(&As[row * 64 + slot * 8 + (cs & 1) * 4]) = h;
      }
    } else {
#pragma unroll
      for (int c = 0; c < 4; ++c) {
        int br = w * 32 + c * 8;
        const u16* g = xbp + (size_t)(m0 + br + lr) * KD + k0 + csrc * 8;
        async16(g, &As[br * 64]);
      }
    }

    if constexpr (WQ) {
#pragma unroll
      for (int it = 0; it < 4; ++it) {
        int qi = it * 256 + tid;
        int row = qi >> 3, p8 = qi & 7;
        int nrow = n0 + row;
        int g = k0 >> 7;
        float s = scale[nrow * GRP + g];
        float bz = -s * zp[nrow * GRP + g];
        unsigned qv = (unsigned)qw[(size_t)nrow * (KD / 8) + (k0 >> 3) + p8];
        u16x8 hv;
#pragma unroll
        for (int i = 0; i < 8; ++i)
          hv[i] = f2bf(fmaf((float)((qv >> (4 * i)) & 15u), s, bz));
        *(u16x8*)(&Bs[row * 64 + ((p8 ^ (row & 7)) * 8)]) = hv;
      }
    } else {
#pragma unroll
      for (int c = 0; c < 4; ++c) {
        int br = w * 32 + c * 8;
        const u16* g = wbp + (size_t)(n0 + br + lr) * KD + k0 + csrc * 8;
        async16(g, &Bs[br * 64]);
      }
    }

    __syncthreads();

#pragma unroll
    for (int kk = 0; kk < 2; ++kk) {
      bf16x8 a[4], b[4];
      const int slot = ((kk * 4 + quad) ^ rsw) * 8;
#pragma unroll
      for (int i = 0; i < 4; ++i)
        a[i] = *(const bf16x8*)&As[(wm + i * 16 + col) * 64 + slot];
#pragma unroll
      for (int j = 0; j < 4; ++j)
        b[j] = *(const bf16x8*)&Bs[(wn + j * 16 + col) * 64 + slot];
#pragma unroll
      for (int i = 0; i < 4; ++i)
#pragma unroll
        for (int j = 0; j < 4; ++j)
          acc[i][j] = __builtin_amdgcn_mfma_f32_16x16x32_bf16(a[i], b[j], acc[i][j], 0, 0, 0);
    }
  }

#pragma unroll
  for (int j = 0; j < 4; ++j) {
    int n = n0 + wn + j * 16 + col;
    float bj = bias[n];
#pragma unroll
    for (int i = 0; i < 4; ++i) {
      int mrow = m0 + wm + i * 16 + quad * 4;
#pragma unroll
      for (int rr = 0; rr < 4; ++rr)
        out[(size_t)(mrow + rr) * ND + n] = acc[i][j][rr] + bj;
    }
  }
}

extern "C" void kernel_launch(void* const* d_in, const int* in_sizes, int n_in,
                              void* d_out, int out_size, void* d_ws, size_t ws_size,
                              hipStream_t stream) {
  const float* x     = (const float*)d_in[0];
  const int*   qw    = (const int*)d_in[1];
  const float* scale = (const float*)d_in[2];
  const float* zp    = (const float*)d_in[3];
  const float* bias  = (const float*)d_in[4];
  float* out = (float*)d_out;

  const int M = in_sizes[0] / KD;  // 8192

  const size_t needW = (size_t)ND * KD * sizeof(u16);  // 32 MB
  const size_t needX = (size_t)M * KD * sizeof(u16);   // 64 MB

  if (ws_size >= needW + needX && (M % 256) == 0) {
    u16* wb = (u16*)d_ws;
    u16* xbuf = wb + (size_t)ND * KD;
    prep_kernel<<<2048, 256, 0, stream>>>(qw, scale, zp, wb,
                                          (const float4*)x, (u16x4*)xbuf,
                                          M * (KD / 4));
    dim3 grid(ND / 256, M / 256);
    gemm256<<<grid, dim3(512), 0, stream>>>(xbuf, wb, bias, out);
  } else if (ws_size >= needW) {
    u16* wb = (u16*)d_ws;
    prep_kernel<<<2048, 256, 0, stream>>>(qw, scale, zp, wb, nullptr, nullptr, 0);
    dim3 grid(ND / 128, M / 128);
    gemm_kernel<1, 0><<<grid, dim3(256), 0, stream>>>(nullptr, x, wb, qw, scale, zp, bias, out);
  } else {
    dim3 grid(ND / 128, M / 128);
    gemm_kernel<1, 1><<<grid, dim3(256), 0, stream>>>(nullptr, x, nullptr, qw, scale, zp, bias, out);
  }
}

// Round 2
// 488.158 us; speedup vs baseline: 1.0229x; 1.0229x over previous
//
#include <hip/hip_runtime.h>

// Problem dims (fixed by setup_inputs): B=4,S=2048 -> M=8192; K=4096; N=4096; bits=4; group=128
#define KD 4096
#define ND 4096
#define GRP 32          // K / group_size = scale groups per output row
#define NT (KD / 64)    // 64 K-tiles of BK=64

typedef unsigned short u16;
typedef float   f32x4  __attribute__((ext_vector_type(4)));
typedef __bf16  bf16x8 __attribute__((ext_vector_type(8)));
typedef unsigned short u16x8 __attribute__((ext_vector_type(8)));
typedef unsigned short u16x4 __attribute__((ext_vector_type(4)));

__device__ __forceinline__ u16 f2bf(float f) {        // RNE float->bf16
  unsigned u = __float_as_uint(f);
  return (u16)((u + 0x7fffu + ((u >> 16) & 1u)) >> 16);
}

__device__ __forceinline__ void async16(const void* g, void* l) {
  // global -> LDS direct copy, 16B per lane, dest = wave-uniform base + lane*16
  __builtin_amdgcn_global_load_lds(
      (const __attribute__((address_space(1))) unsigned int*)g,
      (__attribute__((address_space(3))) unsigned int*)l, 16, 0, 0);
}

// ---------------- prepass: grid-stride, 2048 blocks ----------------
// W: N*K/8 = 2,097,152 int32 -> 4 iters/thread. x: M*K/4 = 8,388,608 float4 -> 16 iters.
__global__ __launch_bounds__(256) void prep_kernel(
    const int* __restrict__ qw, const float* __restrict__ scale,
    const float* __restrict__ zp, u16* __restrict__ wout,
    const float4* __restrict__ x, u16x4* __restrict__ xb, int nx) {
  const int nth = gridDim.x * 256;
  const int t0 = blockIdx.x * 256 + threadIdx.x;
  for (int idx = t0; idx < ND * (KD / 8); idx += nth) {
    int n = idx >> 9;                           // K/8 = 512 int32 per row
    int p = idx & 511;
    int g = p >> 4;                             // 8 values/int32, 128/group
    float s = scale[n * GRP + g];
    float bz = -s * zp[n * GRP + g];            // w = q*s - s*zp
    unsigned q = (unsigned)qw[idx];
    u16x8 hv;
#pragma unroll
    for (int i = 0; i < 8; ++i)
      hv[i] = f2bf(fmaf((float)((q >> (4 * i)) & 15u), s, bz));
    *(u16x8*)(wout + (size_t)idx * 8) = hv;
  }
  for (int i = t0; i < nx; i += nth) {
    float4 v = x[i];
    u16x4 h;
    h[0] = f2bf(v.x); h[1] = f2bf(v.y); h[2] = f2bf(v.z); h[3] = f2bf(v.w);
    xb[i] = h;
  }
}

// ---------------- main GEMM: 256x256 tile, BK=64, 4-phase deep-pipelined ----
// Round-2 fixes vs round-1 (296us):
//  (1) NO "memory" clobbers / asm barriers in the hot loop. Round-1's
//      asm("s_barrier":::"memory") x8/tile likely forced conservative vmcnt(0)
//      drains at every barrier -> synchronous staging. Now: builtin s_barrier +
//      bare s_waitcnt asm + sched_barrier(0) pins (the m201-verified pattern).
//  (2) Deeper stage rotation. WAR windows per region: B-halves of tile t are
//      read only at P0/P1 (j<2 @P0, j>=2 @P1); A-halves at P0/P2 (i<4 / i>=4).
//      Schedule per tile t:  P0: stage A(t+1,h0)   [other buffer, free]
//                            P1: stage A(t+1,h1)   [other buffer, free]
//                            P2: stage B(t+2,h0)   [this buffer, B free after P1]
//                            P3: stage B(t+2,h1)
//      vmcnt(4) once per tile at P3 keeps B(t+2,*) in flight, drains tile t+1.
//      Newest drained load (A(t+1,h1)@P1) has a 2-phase lead; B(t+1,*) has 5.
// LDS swizzle (0-conflict verified): 16B chunk c of row r at slot c^(r&7);
// global_load_lds dest is linear, so lane l pre-fetches source chunk (l&7)^(l>>3).
// C/D: col = lane&15, row = (lane>>4)*4 + reg   [m89/m91-verified]
__global__ __launch_bounds__(512, 2) void gemm256(
    const u16* __restrict__ xb, const u16* __restrict__ wb,
    const float* __restrict__ bias, float* __restrict__ out) {
  __shared__ u16 As[2][256 * 64];
  __shared__ u16 Bs[2][256 * 64];
  const int tid = threadIdx.x;
  const int l = tid & 63, w = tid >> 6;
  const int wr = w >> 2, wc = w & 3;
  const int col = l & 15, quad = l >> 4, rsw = col & 7;
  const int lr = l >> 3, csrc = (l & 7) ^ lr;

  // bijective XCD-chunked swizzle (m204)
  const int id = blockIdx.y * gridDim.x + blockIdx.x;
  const int nwg = gridDim.x * gridDim.y;
  const int q = nwg >> 3, r = nwg & 7;
  const int xcd = id & 7, off = id >> 3;
  const int wgid = (xcd < r ? xcd * (q + 1) : r * (q + 1) + (xcd - r) * q) + off;
  const int nb = gridDim.x;
  const int m0 = (wgid / nb) * 256;
  const int n0 = (wgid % nb) * 256;

  const u16* asrc = xb + (size_t)(m0 + w * 16 + lr) * KD + csrc * 8;
  const u16* bsrc = wb + (size_t)(n0 + w * 16 + lr) * KD + csrc * 8;

#define STAGE_A(t, h)                                                      \
  do {                                                                     \
    const u16* _g = asrc + (size_t)((h) * 128) * KD + (t) * 64;            \
    u16* _l = &As[(t) & 1][((h) * 128 + w * 16) * 64];                     \
    async16(_g, _l);                                                       \
    async16(_g + (size_t)8 * KD, _l + 8 * 64);                             \
  } while (0)
#define STAGE_B(t, h)                                                      \
  do {                                                                     \
    const u16* _g = bsrc + (size_t)((h) * 128) * KD + (t) * 64;            \
    u16* _l = &Bs[(t) & 1][((h) * 128 + w * 16) * 64];                     \
    async16(_g, _l);                                                       \
    async16(_g + (size_t)8 * KD, _l + 8 * 64);                             \
  } while (0)
#define BAR()   __builtin_amdgcn_s_barrier()
#define SB0()   __builtin_amdgcn_sched_barrier(0)
#define LGKM0() do { asm volatile("s_waitcnt lgkmcnt(0)"); SB0(); } while (0)
#define LDA(Ab, i, kk) \
  (*(const bf16x8*)&(Ab)[(wr * 128 + (i) * 16 + col) * 64 + ((((kk) * 4 + quad) ^ rsw) * 8)])
#define LDB(Bb, j, kk) \
  (*(const bf16x8*)&(Bb)[(wc * 64 + (j) * 16 + col) * 64 + ((((kk) * 4 + quad) ^ rsw) * 8)])

  f32x4 acc[8][4] = {};
  bf16x8 a[4][2], b[4][2];

  // prologue: tile0 fully + B(1,*) in flight; vmcnt(4) lands tile0, keeps B(1,*)
  STAGE_A(0, 0); STAGE_A(0, 1); STAGE_B(0, 0); STAGE_B(0, 1);
  STAGE_B(1, 0); STAGE_B(1, 1);
  asm volatile("s_waitcnt vmcnt(4)");
  SB0();
  BAR();

  for (int t = 0; t < NT; ++t) {
    const u16* Ab = As[t & 1];
    const u16* Bb = Bs[t & 1];

    // ---- P0: read a-lo + b-lo, stage A(t+1,h0), MFMA lo x lo ----
#pragma unroll
    for (int i = 0; i < 4; ++i) { a[i][0] = LDA(Ab, i, 0); a[i][1] = LDA(Ab, i, 1); }
#pragma unroll
    for (int j = 0; j < 2; ++j) { b[j][0] = LDB(Bb, j, 0); b[j][1] = LDB(Bb, j, 1); }
    if (t + 1 < NT) STAGE_A(t + 1, 0);
    BAR();
    LGKM0();
    __builtin_amdgcn_s_setprio(1);
#pragma unroll
    for (int kk = 0; kk < 2; ++kk)
#pragma unroll
      for (int i = 0; i < 4; ++i)
#pragma unroll
        for (int j = 0; j < 2; ++j)
          acc[i][j] = __builtin_amdgcn_mfma_f32_16x16x32_bf16(a[i][kk], b[j][kk], acc[i][j], 0, 0, 0);
    __builtin_amdgcn_s_setprio(0);
    BAR();

    // ---- P1: read b-hi, stage A(t+1,h1), MFMA lo x hi ----
#pragma unroll
    for (int j = 2; j < 4; ++j) { b[j][0] = LDB(Bb, j, 0); b[j][1] = LDB(Bb, j, 1); }
    if (t + 1 < NT) STAGE_A(t + 1, 1);
    BAR();
    LGKM0();
    __builtin_amdgcn_s_setprio(1);
#pragma unroll
    for (int kk = 0; kk < 2; ++kk)
#pragma unroll
      for (int i = 0; i < 4; ++i)
#pragma unroll
        for (int j = 2; j < 4; ++j)
          acc[i][j] = __builtin_amdgcn_mfma_f32_16x16x32_bf16(a[i][kk], b[j][kk], acc[i][j], 0, 0, 0);
    __builtin_amdgcn_s_setprio(0);
    BAR();

    // ---- P2: read a-hi (reuse regs, a-lo dead), stage B(t+2,h0), MFMA hi x lo ----
#pragma unroll
    for (int i = 0; i < 4; ++i) { a[i][0] = LDA(Ab, i + 4, 0); a[i][1] = LDA(Ab, i + 4, 1); }
    if (t + 2 < NT) STAGE_B(t + 2, 0);
    BAR();
    LGKM0();
    __builtin_amdgcn_s_setprio(1);
#pragma unroll
    for (int kk = 0; kk < 2; ++kk)
#pragma unroll
      for (int i = 0; i < 4; ++i)
#pragma unroll
        for (int j = 0; j < 2; ++j)
          acc[4 + i][j] = __builtin_amdgcn_mfma_f32_16x16x32_bf16(a[i][kk], b[j][kk], acc[4 + i][j], 0, 0, 0);
    __builtin_amdgcn_s_setprio(0);
    BAR();

    // ---- P3: stage B(t+2,h1), MFMA hi x hi, counted vmcnt ----
    if (t + 2 < NT) STAGE_B(t + 2, 1);
    __builtin_amdgcn_s_setprio(1);
#pragma unroll
    for (int kk = 0; kk < 2; ++kk)
#pragma unroll
      for (int i = 0; i < 4; ++i)
#pragma unroll
        for (int j = 2; j < 4; ++j)
          acc[4 + i][j] = __builtin_amdgcn_mfma_f32_16x16x32_bf16(a[i][kk], b[j][kk], acc[4 + i][j], 0, 0, 0);
    __builtin_amdgcn_s_setprio(0);
    if (t + 2 < NT) { asm volatile("s_waitcnt vmcnt(4)"); }
    else            { asm volatile("s_waitcnt vmcnt(0)"); }
    SB0();
    BAR();
    SB0();
  }

  // epilogue: add bias, store fp32
#pragma unroll
  for (int j = 0; j < 4; ++j) {
    int n = n0 + wc * 64 + j * 16 + col;
    float bj = bias[n];
#pragma unroll
    for (int i = 0; i < 8; ++i) {
      int mrow = m0 + wr * 128 + i * 16 + quad * 4;
#pragma unroll
      for (int rr = 0; rr < 4; ++rr)
        out[(size_t)(mrow + rr) * ND + n] = acc[i][j][rr] + bj;
    }
  }
#undef STAGE_A
#undef STAGE_B
#undef BAR
#undef SB0
#undef LGKM0
#undef LDA
#undef LDB
}

// ---------------- fallback GEMM (old 128x128 m97-style kernel, kept for small ws) ----
template <int XF32, int WQ>
__global__ __launch_bounds__(256, 3) void gemm_kernel(
    const u16*   __restrict__ xbp,
    const float* __restrict__ xf,
    const u16*   __restrict__ wbp,
    const int*   __restrict__ qw,
    const float* __restrict__ scale,
    const float* __restrict__ zp,
    const float* __restrict__ bias,
    float* __restrict__ out) {
  __shared__ u16 As[128 * 64];
  __shared__ u16 Bs[128 * 64];
  const int tid = threadIdx.x;
  const int l = tid & 63, w = tid >> 6;
  const int m0 = blockIdx.y * 128, n0 = blockIdx.x * 128;
  const int wm = (w >> 1) * 64, wn = (w & 1) * 64;
  const int col = l & 15, quad = l >> 4;
  const int rsw = col & 7;
  const int lr = l >> 3;
  const int csrc = (l & 7) ^ lr;
  f32x4 acc[4][4] = {};

  for (int k0 = 0; k0 < KD; k0 += 64) {
    __syncthreads();

    if constexpr (XF32) {
#pragma unroll
      for (int it = 0; it < 8; ++it) {
        int fi = it * 256 + tid;
        int row = fi >> 4, cs = fi & 15;
        float4 v = *(const float4*)(xf + (size_t)(m0 + row) * KD + k0 + cs * 4);
        u16x4 h;
        h[0] = f2bf(v.x); h[1] = f2bf(v.y); h[2] = f2bf(v.z); h[3] = f2bf(v.w);
        int slot = (cs >> 1) ^ (row & 7);
        *(u16x4*)(&As[row * 64 + slot * 8 + (cs & 1) * 4]) = h;
      }
    } else {
#pragma unroll
      for (int c = 0; c < 4; ++c) {
        int br = w * 32 + c * 8;
        const u16* g = xbp + (size_t)(m0 + br + lr) * KD + k0 + csrc * 8;
        async16(g, &As[br * 64]);
      }
    }

    if constexpr (WQ) {
#pragma unroll
      for (int it = 0; it < 4; ++it) {
        int qi = it * 256 + tid;
        int row = qi >> 3, p8 = qi & 7;
        int nrow = n0 + row;
        int g = k0 >> 7;
        float s = scale[nrow * GRP + g];
        float bz = -s * zp[nrow * GRP + g];
        unsigned qv = (unsigned)qw[(size_t)nrow * (KD / 8) + (k0 >> 3) + p8];
        u16x8 hv;
#pragma unroll
        for (int i = 0; i < 8; ++i)
          hv[i] = f2bf(fmaf((float)((qv >> (4 * i)) & 15u), s, bz));
        *(u16x8*)(&Bs[row * 64 + ((p8 ^ (row & 7)) * 8)]) = hv;
      }
    } else {
#pragma unroll
      for (int c = 0; c < 4; ++c) {
        int br = w * 32 + c * 8;
        const u16* g = wbp + (size_t)(n0 + br + lr) * KD + k0 + csrc * 8;
        async16(g, &Bs[br * 64]);
      }
    }

    __syncthreads();

#pragma unroll
    for (int kk = 0; kk < 2; ++kk) {
      bf16x8 a[4], b[4];
      const int slot = ((kk * 4 + quad) ^ rsw) * 8;
#pragma unroll
      for (int i = 0; i < 4; ++i)
        a[i] = *(const bf16x8*)&As[(wm + i * 16 + col) * 64 + slot];
#pragma unroll
      for (int j = 0; j < 4; ++j)
        b[j] = *(const bf16x8*)&Bs[(wn + j * 16 + col) * 64 + slot];
#pragma unroll
      for (int i = 0; i < 4; ++i)
#pragma unroll
        for (int j = 0; j < 4; ++j)
          acc[i][j] = __builtin_amdgcn_mfma_f32_16x16x32_bf16(a[i], b[j], acc[i][j], 0, 0, 0);
    }
  }

#pragma unroll
  for (int j = 0; j < 4; ++j) {
    int n = n0 + wn + j * 16 + col;
    float bj = bias[n];
#pragma unroll
    for (int i = 0; i < 4; ++i) {
      int mrow = m0 + wm + i * 16 + quad * 4;
#pragma unroll
      for (int rr = 0; rr < 4; ++rr)
        out[(size_t)(mrow + rr) * ND + n] = acc[i][j][rr] + bj;
    }
  }
}

extern "C" void kernel_launch(void* const* d_in, const int* in_sizes, int n_in,
                              void* d_out, int out_size, void* d_ws, size_t ws_size,
                              hipStream_t stream) {
  const float* x     = (const float*)d_in[0];
  const int*   qw    = (const int*)d_in[1];
  const float* scale = (const float*)d_in[2];
  const float* zp    = (const float*)d_in[3];
  const float* bias  = (const float*)d_in[4];
  float* out = (float*)d_out;

  const int M = in_sizes[0] / KD;  // 8192

  const size_t needW = (size_t)ND * KD * sizeof(u16);  // 32 MB
  const size_t needX = (size_t)M * KD * sizeof(u16);   // 64 MB

  if (ws_size >= needW + needX && (M % 256) == 0) {
    u16* wb = (u16*)d_ws;
    u16* xbuf = wb + (size_t)ND * KD;
    prep_kernel<<<2048, 256, 0, stream>>>(qw, scale, zp, wb,
                                          (const float4*)x, (u16x4*)xbuf,
                                          M * (KD / 4));
    dim3 grid(ND / 256, M / 256);
    gemm256<<<grid, dim3(512), 0, stream>>>(xbuf, wb, bias, out);
  } else if (ws_size >= needW) {
    u16* wb = (u16*)d_ws;
    prep_kernel<<<2048, 256, 0, stream>>>(qw, scale, zp, wb, nullptr, nullptr, 0);
    dim3 grid(ND / 128, M / 128);
    gemm_kernel<1, 0><<<grid, dim3(256), 0, stream>>>(nullptr, x, wb, qw, scale, zp, bias, out);
  } else {
    dim3 grid(ND / 128, M / 128);
    gemm_kernel<1, 1><<<grid, dim3(256), 0, stream>>>(nullptr, x, nullptr, qw, scale, zp, bias, out);
  }
}

// Round 3
// 477.670 us; speedup vs baseline: 1.0453x; 1.0220x over previous
//
#include <hip/hip_runtime.h>

// Problem dims (fixed by setup_inputs): B=4,S=2048 -> M=8192; K=4096; N=4096; bits=4; group=128
#define KD 4096
#define ND 4096
#define GRP 32          // K / group_size = scale groups per output row
#define NT (KD / 64)    // 64 K-tiles of BK=64

typedef unsigned short u16;
typedef float   f32x4  __attribute__((ext_vector_type(4)));
typedef __bf16  bf16x8 __attribute__((ext_vector_type(8)));
typedef unsigned short u16x8 __attribute__((ext_vector_type(8)));
typedef unsigned short u16x4 __attribute__((ext_vector_type(4)));

__device__ __forceinline__ u16 f2bf(float f) {        // RNE float->bf16
  unsigned u = __float_as_uint(f);
  return (u16)((u + 0x7fffu + ((u >> 16) & 1u)) >> 16);
}

__device__ __forceinline__ void async16(const void* g, void* l) {
  // global -> LDS direct copy, 16B per lane, dest = wave-uniform base + lane*16
  __builtin_amdgcn_global_load_lds(
      (const __attribute__((address_space(1))) unsigned int*)g,
      (__attribute__((address_space(3))) unsigned int*)l, 16, 0, 0);
}

// ---------------- prepass: grid-stride, 2048 blocks ----------------
// W: int4-vectorized unpack: N*K/32 = 524288 int4 = exactly 1/thread.
//    4 consecutive int32 share one scale group (16 int32/group, 4-aligned run).
// x: M*K/4 = 8,388,608 float4 -> 16 iters/thread.
__global__ __launch_bounds__(256) void prep_kernel(
    const int* __restrict__ qw, const float* __restrict__ scale,
    const float* __restrict__ zp, u16* __restrict__ wout,
    const float4* __restrict__ x, u16x4* __restrict__ xb, int nx) {
  const int nth = gridDim.x * 256;
  const int t0 = blockIdx.x * 256 + threadIdx.x;
  for (int idx4 = t0; idx4 < ND * (KD / 32); idx4 += nth) {
    int n = idx4 >> 7;                          // 128 int4 per row
    int p4 = idx4 & 127;
    int g = p4 >> 2;                            // 4 int32 per iter, 16 int32/group
    float s = scale[n * GRP + g];
    float bz = -s * zp[n * GRP + g];            // w = q*s - s*zp
    int4 q4 = ((const int4*)qw)[idx4];
    const unsigned qv[4] = {(unsigned)q4.x, (unsigned)q4.y,
                            (unsigned)q4.z, (unsigned)q4.w};
#pragma unroll
    for (int k = 0; k < 4; ++k) {
      u16x8 hv;
#pragma unroll
      for (int i = 0; i < 8; ++i)
        hv[i] = f2bf(fmaf((float)((qv[k] >> (4 * i)) & 15u), s, bz));
      *(u16x8*)(wout + (size_t)idx4 * 32 + k * 8) = hv;
    }
  }
  for (int i = t0; i < nx; i += nth) {
    float4 v = x[i];
    u16x4 h;
    h[0] = f2bf(v.x); h[1] = f2bf(v.y); h[2] = f2bf(v.z); h[3] = f2bf(v.w);
    xb[i] = h;
  }
}

// ---------------- main GEMM: 256x256 tile, BK=64, 4-phase, max-depth pipeline ----
// Round-3 change vs round-2 (283us, MfmaUtil 41.5%): round-2's vmcnt(4) drained
// A(t+1,h1) staged only 2 phases (~310cy) earlier -> ~600cy HBM-latency stall per
// tile ~= the observed 58% idle. Max-depth rotation under the WAR constraints
// (A-halves of a buffer fully read after P2, B-halves after P1):
//   P2: stage B(t+2,h0) + B(t+2,h1)   [B region free after P1]
//   P3: stage A(t+2,h0) + A(t+2,h1)   [A region free after P2]
// 16 loads/thread in flight; ONE vmcnt(8) per tile at P3 drains tile t+1
// (youngest drained load has a 3.5-phase lead, B loads 6-phase).
// Loop peeled: 2-tile unroll (compile-time buffer parity), explicit 4-tile tail
// (t=NT-2 waits vmcnt(0) to land tile NT-1; no branches in hot loop).
// LDS swizzle (0-conflict verified): 16B chunk c of row r at slot c^(r&7);
// global_load_lds dest is linear, so lane l pre-fetches source chunk (l&7)^(l>>3).
// C/D: col = lane&15, row = (lane>>4)*4 + reg   [m89/m91-verified]
__global__ __launch_bounds__(512, 2) void gemm256(
    const u16* __restrict__ xb, const u16* __restrict__ wb,
    const float* __restrict__ bias, float* __restrict__ out) {
  __shared__ u16 As[2][256 * 64];
  __shared__ u16 Bs[2][256 * 64];
  const int tid = threadIdx.x;
  const int l = tid & 63, w = tid >> 6;
  const int wr = w >> 2, wc = w & 3;
  const int col = l & 15, quad = l >> 4, rsw = col & 7;
  const int lr = l >> 3, csrc = (l & 7) ^ lr;

  // bijective XCD-chunked swizzle (m204)
  const int id = blockIdx.y * gridDim.x + blockIdx.x;
  const int nwg = gridDim.x * gridDim.y;
  const int q = nwg >> 3, r = nwg & 7;
  const int xcd = id & 7, off = id >> 3;
  const int wgid = (xcd < r ? xcd * (q + 1) : r * (q + 1) + (xcd - r) * q) + off;
  const int nb = gridDim.x;
  const int m0 = (wgid / nb) * 256;
  const int n0 = (wgid % nb) * 256;

  const u16* asrc = xb + (size_t)(m0 + w * 16 + lr) * KD + csrc * 8;
  const u16* bsrc = wb + (size_t)(n0 + w * 16 + lr) * KD + csrc * 8;

#define STAGE_A(t, h)                                                      \
  do {                                                                     \
    const u16* _g = asrc + (size_t)((h) * 128) * KD + (t) * 64;            \
    u16* _l = &As[(t) & 1][((h) * 128 + w * 16) * 64];                     \
    async16(_g, _l);                                                       \
    async16(_g + (size_t)8 * KD, _l + 8 * 64);                             \
  } while (0)
#define STAGE_B(t, h)                                                      \
  do {                                                                     \
    const u16* _g = bsrc + (size_t)((h) * 128) * KD + (t) * 64;            \
    u16* _l = &Bs[(t) & 1][((h) * 128 + w * 16) * 64];                     \
    async16(_g, _l);                                                       \
    async16(_g + (size_t)8 * KD, _l + 8 * 64);                             \
  } while (0)
#define BAR()   __builtin_amdgcn_s_barrier()
#define SB0()   __builtin_amdgcn_sched_barrier(0)
#define LGKM0() do { asm volatile("s_waitcnt lgkmcnt(0)"); SB0(); } while (0)
#define LDA(Ab, i, kk) \
  (*(const bf16x8*)&(Ab)[(wr * 128 + (i) * 16 + col) * 64 + ((((kk) * 4 + quad) ^ rsw) * 8)])
#define LDB(Bb, j, kk) \
  (*(const bf16x8*)&(Bb)[(wc * 64 + (j) * 16 + col) * 64 + ((((kk) * 4 + quad) ^ rsw) * 8)])
#define MFMA_BLK(IO, JO)                                                   \
  _Pragma("unroll")                                                        \
  for (int kk = 0; kk < 2; ++kk)                                           \
    _Pragma("unroll")                                                      \
    for (int i = 0; i < 4; ++i)                                            \
      _Pragma("unroll")                                                    \
      for (int j = 0; j < 2; ++j)                                          \
        acc[(IO) + i][(JO) + j] = __builtin_amdgcn_mfma_f32_16x16x32_bf16( \
            a[i][kk], b[(JO) + j][kk], acc[(IO) + i][(JO) + j], 0, 0, 0);
// One K-tile = 4 phases. SB_STMT issues B-stages (P2), SA_STMT A-stages (P3),
// WAIT_STMT is the once-per-tile counted vmcnt.
#define TILE(Ab, Bb, SB_STMT, SA_STMT, WAIT_STMT)                          \
  do {                                                                     \
    _Pragma("unroll")                                                      \
    for (int i = 0; i < 4; ++i) { a[i][0] = LDA(Ab, i, 0); a[i][1] = LDA(Ab, i, 1); } \
    _Pragma("unroll")                                                      \
    for (int j = 0; j < 2; ++j) { b[j][0] = LDB(Bb, j, 0); b[j][1] = LDB(Bb, j, 1); } \
    BAR(); LGKM0();                                                        \
    __builtin_amdgcn_s_setprio(1); MFMA_BLK(0, 0);                         \
    __builtin_amdgcn_s_setprio(0); BAR();                                  \
    _Pragma("unroll")                                                      \
    for (int j = 2; j < 4; ++j) { b[j][0] = LDB(Bb, j, 0); b[j][1] = LDB(Bb, j, 1); } \
    BAR(); LGKM0();                                                        \
    __builtin_amdgcn_s_setprio(1); MFMA_BLK(0, 2);                         \
    __builtin_amdgcn_s_setprio(0); BAR();                                  \
    _Pragma("unroll")                                                      \
    for (int i = 0; i < 4; ++i) { a[i][0] = LDA(Ab, i + 4, 0); a[i][1] = LDA(Ab, i + 4, 1); } \
    SB_STMT;                                                               \
    BAR(); LGKM0();                                                        \
    __builtin_amdgcn_s_setprio(1); MFMA_BLK(4, 0);                         \
    __builtin_amdgcn_s_setprio(0); BAR();                                  \
    SA_STMT;                                                               \
    __builtin_amdgcn_s_setprio(1); MFMA_BLK(4, 2);                         \
    __builtin_amdgcn_s_setprio(0);                                         \
    WAIT_STMT; SB0(); BAR();                                               \
  } while (0)

  f32x4 acc[8][4] = {};
  bf16x8 a[4][2], b[4][2];

  // prologue: tiles 0 and 1 fully in flight (16 loads, B-then-A order matching
  // steady state); vmcnt(8) lands tile 0, keeps tile 1's 8 outstanding.
  STAGE_B(0, 0); STAGE_B(0, 1); STAGE_A(0, 0); STAGE_A(0, 1);
  STAGE_B(1, 0); STAGE_B(1, 1); STAGE_A(1, 0); STAGE_A(1, 1);
  asm volatile("s_waitcnt vmcnt(8)");
  SB0();
  BAR();

  for (int tt = 0; tt < NT - 4; tt += 2) {
    TILE(As[0], Bs[0],
         { STAGE_B(tt + 2, 0); STAGE_B(tt + 2, 1); },
         { STAGE_A(tt + 2, 0); STAGE_A(tt + 2, 1); },
         asm volatile("s_waitcnt vmcnt(8)"));
    TILE(As[1], Bs[1],
         { STAGE_B(tt + 3, 0); STAGE_B(tt + 3, 1); },
         { STAGE_A(tt + 3, 0); STAGE_A(tt + 3, 1); },
         asm volatile("s_waitcnt vmcnt(8)"));
  }
  TILE(As[0], Bs[0],
       { STAGE_B(NT - 2, 0); STAGE_B(NT - 2, 1); },
       { STAGE_A(NT - 2, 0); STAGE_A(NT - 2, 1); },
       asm volatile("s_waitcnt vmcnt(8)"));
  TILE(As[1], Bs[1],
       { STAGE_B(NT - 1, 0); STAGE_B(NT - 1, 1); },
       { STAGE_A(NT - 1, 0); STAGE_A(NT - 1, 1); },
       asm volatile("s_waitcnt vmcnt(8)"));
  TILE(As[0], Bs[0], {;}, {;}, asm volatile("s_waitcnt vmcnt(0)"));  // lands tile NT-1
  TILE(As[1], Bs[1], {;}, {;}, ;);

  // epilogue: add bias, store fp32
#pragma unroll
  for (int j = 0; j < 4; ++j) {
    int n = n0 + wc * 64 + j * 16 + col;
    float bj = bias[n];
#pragma unroll
    for (int i = 0; i < 8; ++i) {
      int mrow = m0 + wr * 128 + i * 16 + quad * 4;
#pragma unroll
      for (int rr = 0; rr < 4; ++rr)
        out[(size_t)(mrow + rr) * ND + n] = acc[i][j][rr] + bj;
    }
  }
#undef STAGE_A
#undef STAGE_B
#undef BAR
#undef SB0
#undef LGKM0
#undef LDA
#undef LDB
#undef MFMA_BLK
#undef TILE
}

// ---------------- fallback GEMM (old 128x128 m97-style kernel, kept for small ws) ----
template <int XF32, int WQ>
__global__ __launch_bounds__(256, 3) void gemm_kernel(
    const u16*   __restrict__ xbp,
    const float* __restrict__ xf,
    const u16*   __restrict__ wbp,
    const int*   __restrict__ qw,
    const float* __restrict__ scale,
    const float* __restrict__ zp,
    const float* __restrict__ bias,
    float* __restrict__ out) {
  __shared__ u16 As[128 * 64];
  __shared__ u16 Bs[128 * 64];
  const int tid = threadIdx.x;
  const int l = tid & 63, w = tid >> 6;
  const int m0 = blockIdx.y * 128, n0 = blockIdx.x * 128;
  const int wm = (w >> 1) * 64, wn = (w & 1) * 64;
  const int col = l & 15, quad = l >> 4;
  const int rsw = col & 7;
  const int lr = l >> 3;
  const int csrc = (l & 7) ^ lr;
  f32x4 acc[4][4] = {};

  for (int k0 = 0; k0 < KD; k0 += 64) {
    __syncthreads();

    if constexpr (XF32) {
#pragma unroll
      for (int it = 0; it < 8; ++it) {
        int fi = it * 256 + tid;
        int row = fi >> 4, cs = fi & 15;
        float4 v = *(const float4*)(xf + (size_t)(m0 + row) * KD + k0 + cs * 4);
        u16x4 h;
        h[0] = f2bf(v.x); h[1] = f2bf(v.y); h[2] = f2bf(v.z); h[3] = f2bf(v.w);
        int slot = (cs >> 1) ^ (row & 7);
        *(u16x4*)(&As[row * 64 + slot * 8 + (cs & 1) * 4]) = h;
      }
    } else {
#pragma unroll
      for (int c = 0; c < 4; ++c) {
        int br = w * 32 + c * 8;
        const u16* g = xbp + (size_t)(m0 + br + lr) * KD + k0 + csrc * 8;
        async16(g, &As[br * 64]);
      }
    }

    if constexpr (WQ) {
#pragma unroll
      for (int it = 0; it < 4; ++it) {
        int qi = it * 256 + tid;
        int row = qi >> 3, p8 = qi & 7;
        int nrow = n0 + row;
        int g = k0 >> 7;
        float s = scale[nrow * GRP + g];
        float bz = -s * zp[nrow * GRP + g];
        unsigned qv = (unsigned)qw[(size_t)nrow * (KD / 8) + (k0 >> 3) + p8];
        u16x8 hv;
#pragma unroll
        for (int i = 0; i < 8; ++i)
          hv[i] = f2bf(fmaf((float)((qv >> (4 * i)) & 15u), s, bz));
        *(u16x8*)(&Bs[row * 64 + ((p8 ^ (row & 7)) * 8)]) = hv;
      }
    } else {
#pragma unroll
      for (int c = 0; c < 4; ++c) {
        int br = w * 32 + c * 8;
        const u16* g = wbp + (size_t)(n0 + br + lr) * KD + k0 + csrc * 8;
        async16(g, &Bs[br * 64]);
      }
    }

    __syncthreads();

#pragma unroll
    for (int kk = 0; kk < 2; ++kk) {
      bf16x8 a[4], b[4];
      const int slot = ((kk * 4 + quad) ^ rsw) * 8;
#pragma unroll
      for (int i = 0; i < 4; ++i)
        a[i] = *(const bf16x8*)&As[(wm + i * 16 + col) * 64 + slot];
#pragma unroll
      for (int j = 0; j < 4; ++j)
        b[j] = *(const bf16x8*)&Bs[(wn + j * 16 + col) * 64 + slot];
#pragma unroll
      for (int i = 0; i < 4; ++i)
#pragma unroll
        for (int j = 0; j < 4; ++j)
          acc[i][j] = __builtin_amdgcn_mfma_f32_16x16x32_bf16(a[i], b[j], acc[i][j], 0, 0, 0);
    }
  }

#pragma unroll
  for (int j = 0; j < 4; ++j) {
    int n = n0 + wn + j * 16 + col;
    float bj = bias[n];
#pragma unroll
    for (int i = 0; i < 4; ++i) {
      int mrow = m0 + wm + i * 16 + quad * 4;
#pragma unroll
      for (int rr = 0; rr < 4; ++rr)
        out[(size_t)(mrow + rr) * ND + n] = acc[i][j][rr] + bj;
    }
  }
}

extern "C" void kernel_launch(void* const* d_in, const int* in_sizes, int n_in,
                              void* d_out, int out_size, void* d_ws, size_t ws_size,
                              hipStream_t stream) {
  const float* x     = (const float*)d_in[0];
  const int*   qw    = (const int*)d_in[1];
  const float* scale = (const float*)d_in[2];
  const float* zp    = (const float*)d_in[3];
  const float* bias  = (const float*)d_in[4];
  float* out = (float*)d_out;

  const int M = in_sizes[0] / KD;  // 8192

  const size_t needW = (size_t)ND * KD * sizeof(u16);  // 32 MB
  const size_t needX = (size_t)M * KD * sizeof(u16);   // 64 MB

  if (ws_size >= needW + needX && (M % 256) == 0) {
    u16* wb = (u16*)d_ws;
    u16* xbuf = wb + (size_t)ND * KD;
    prep_kernel<<<2048, 256, 0, stream>>>(qw, scale, zp, wb,
                                          (const float4*)x, (u16x4*)xbuf,
                                          M * (KD / 4));
    dim3 grid(ND / 256, M / 256);
    gemm256<<<grid, dim3(512), 0, stream>>>(xbuf, wb, bias, out);
  } else if (ws_size >= needW) {
    u16* wb = (u16*)d_ws;
    prep_kernel<<<2048, 256, 0, stream>>>(qw, scale, zp, wb, nullptr, nullptr, 0);
    dim3 grid(ND / 128, M / 128);
    gemm_kernel<1, 0><<<grid, dim3(256), 0, stream>>>(nullptr, x, wb, qw, scale, zp, bias, out);
  } else {
    dim3 grid(ND / 128, M / 128);
    gemm_kernel<1, 1><<<grid, dim3(256), 0, stream>>>(nullptr, x, nullptr, qw, scale, zp, bias, out);
  }
}